// Round 1
// baseline (11804.284 us; speedup 1.0000x reference)
//
#include <hip/hip_runtime.h>
#include <math.h>

constexpr int cNS = 64, cNV = 32, cNB = 8, cL = 4, cEMB = 32, cNT = 10;
constexpr float PI_F = 3.14159265358979323846f;
constexpr float INV_SQRT_NN = 0.17677669529663687f;   // 1/sqrt(32)
constexpr float BESSEL_C = 2.3094010767585034f;       // sqrt(2/3)*sqrt(8)
constexpr float SQRT3 = 1.7320508075688772f;

// ---------------- precompute kernels ----------------

// A[l][t][u][m] = sum_e emb[t][e] * W_sc_s[l][u][e][m]   (u<64, m<96)
__global__ void k_precompA(const float* __restrict__ emb, const float* __restrict__ Wss,
                           float* __restrict__ A) {
  int idx = blockIdx.x * 256 + threadIdx.x;
  if (idx >= cL * cNT * 64 * 96) return;
  int m = idx % 96;
  int u = (idx / 96) % 64;
  int t = (idx / (96 * 64)) % cNT;
  int l = idx / (96 * 64 * cNT);
  float acc = 0.f;
#pragma unroll
  for (int e = 0; e < 32; ++e)
    acc += emb[t * 32 + e] * Wss[((size_t)(l * 64 + u) * 32 + e) * 96 + m];
  A[idx] = acc;
}

// B[l][t][u][vo] = sum_e emb[t][e] * W_sc_v[l][u][e][vo]   (u<32, vo<32)
__global__ void k_precompB(const float* __restrict__ emb, const float* __restrict__ Wsv_,
                           float* __restrict__ B) {
  int idx = blockIdx.x * 256 + threadIdx.x;
  if (idx >= cL * cNT * 32 * 32) return;
  int vo = idx % 32;
  int u = (idx / 32) % 32;
  int t = (idx / 1024) % cNT;
  int l = idx / (1024 * cNT);
  float acc = 0.f;
#pragma unroll
  for (int e = 0; e < 32; ++e)
    acc += emb[t * 32 + e] * Wsv_[((size_t)(l * 32 + u) * 32 + e) * 32 + vo];
  B[idx] = acc;
}

// fc2T[l][o][j] = fc2[l][j][o] ; fc1T[l][j][t] = fc1[l][t][j]
__global__ void k_transpose_fc(const float* __restrict__ fc1, const float* __restrict__ fc2,
                               float* __restrict__ fc1T, float* __restrict__ fc2T) {
  int idx = blockIdx.x * 256 + threadIdx.x;
  if (idx < cL * 12288) {
    int l = idx / 12288, p = idx % 12288;
    int o = p / 64, j = p % 64;
    fc2T[idx] = fc2[l * 12288 + j * 192 + o];
  }
  if (idx < cL * 1024) {
    int l = idx / 1024, p = idx % 1024;
    int j = p / 16, t = p % 16;
    fc1T[idx] = fc1[l * 1024 + t * 64 + j];
  }
}

// v[n][vc][c] = x[n][c]*Wup[0][vc] + x[n][3+c]*Wup[1][vc]; v_old=v; xcur=x
__global__ void k_init(const float* __restrict__ x, const float* __restrict__ Wup,
                       float* __restrict__ v, float* __restrict__ v_old,
                       float* __restrict__ xcur, int N) {
  int idx = blockIdx.x * 256 + threadIdx.x;
  if (idx >= N * 32) return;
  int n = idx >> 5, vc = idx & 31;
  float w0 = Wup[vc], w1 = Wup[32 + vc];
#pragma unroll
  for (int c = 0; c < 3; ++c) {
    float val = x[n * 6 + c] * w0 + x[n * 6 + 3 + c] * w1;
    v[idx * 3 + c] = val;
    v_old[idx * 3 + c] = val;
  }
  if (vc < 6) xcur[n * 6 + vc] = x[n * 6 + vc];
}

// ---------------- edge kernel (one thread per edge) ----------------
template <bool SZERO>
__global__ __launch_bounds__(256, 2) void k_edge(
    const float* __restrict__ xcur, const float* __restrict__ s, const float* __restrict__ v,
    const int* __restrict__ esrc, const int* __restrict__ edst,
    const float* __restrict__ fc1T, const float* __restrict__ b1,
    const float* __restrict__ fc2T, const float* __restrict__ Wsv,
    const float* __restrict__ Wvs, float* __restrict__ agg_s, float* __restrict__ agg_v,
    int E) {
  __shared__ float sf1[1024];    // fc1T  [j][t]
  __shared__ float sb1v[64];
  __shared__ float sf2[12288];   // fc2T  [o][j]
  for (int i = threadIdx.x; i < 1024; i += 256) sf1[i] = fc1T[i];
  if (threadIdx.x < 64) sb1v[threadIdx.x] = b1[threadIdx.x];
  for (int i = threadIdx.x; i < 12288; i += 256) sf2[i] = fc2T[i];
  __syncthreads();

  int e = blockIdx.x * 256 + threadIdx.x;
  if (e >= E) return;
  int src = esrc[e], dst = edst[e];

  float xsrc[6], xdst[6];
  {
    const float2* ps = (const float2*)(xcur + (size_t)src * 6);
    const float2* pd = (const float2*)(xcur + (size_t)dst * 6);
    float2 A0 = ps[0], A1 = ps[1], A2 = ps[2];
    float2 B0 = pd[0], B1 = pd[1], B2 = pd[2];
    xsrc[0] = A0.x; xsrc[1] = A0.y; xsrc[2] = A1.x; xsrc[3] = A1.y; xsrc[4] = A2.x; xsrc[5] = A2.y;
    xdst[0] = B0.x; xdst[1] = B0.y; xdst[2] = B1.x; xdst[3] = B1.y; xdst[4] = B2.x; xdst[5] = B2.y;
  }

  float f[16];
  float a00, a01, a02, a10, a11, a12;
#pragma unroll
  for (int i = 0; i < 2; ++i) {
    float vx = xsrc[3 * i + 0] - xdst[3 * i + 0];
    float vy = xsrc[3 * i + 1] - xdst[3 * i + 1];
    float vz = xsrc[3 * i + 2] - xdst[3 * i + 2];
    float r2 = vx * vx + vy * vy + vz * vz;
    float r = sqrtf(r2);
    float invr = 1.0f / r;
    float th = (PI_F / 3.0f) * r;
    float s1, c1;
    __sincosf(th, &s1, &c1);
    float twc = 2.0f * c1;
    float snm = 0.f, sn = s1;
    float fc = BESSEL_C * invr;
#pragma unroll
    for (int nn = 0; nn < 8; ++nn) {
      f[8 * i + nn] = fc * sn;
      float nx = twc * sn - snm;
      snm = sn;
      sn = nx;
    }
    float uu = (2.0f / 3.0f) * r - 2.0f;   // 2*(r/3 - 1)
    float cut;
    if (uu > 0.f) cut = 0.f;
    else if (uu < -1.f) cut = 1.f;
    else cut = (1.0f - __cosf(PI_F * uu)) * 0.5f;
    float sc = cut * SQRT3 * invr;
    if (i == 0) { a00 = vx * sc; a01 = vy * sc; a02 = vz * sc; }
    else        { a10 = vx * sc; a11 = vy * sc; a12 = vz * sc; }
  }

  // hidden = silu(f @ fc1 + b1)
  float hid[64];
#pragma unroll
  for (int j = 0; j < 64; ++j) {
    const float4* row = (const float4*)(sf1 + j * 16);
    float4 w0 = row[0], w1 = row[1], w2 = row[2], w3 = row[3];
    float acc = sb1v[j];
    acc += f[0] * w0.x + f[1] * w0.y + f[2] * w0.z + f[3] * w0.w;
    acc += f[4] * w1.x + f[5] * w1.y + f[6] * w1.z + f[7] * w1.w;
    acc += f[8] * w2.x + f[9] * w2.y + f[10] * w2.z + f[11] * w2.w;
    acc += f[12] * w3.x + f[13] * w3.y + f[14] * w3.z + f[15] * w3.w;
    hid[j] = acc * (1.0f / (1.0f + __expf(-acc)));
  }

  // ---- Pass A: q[k][m] = sum_u s_src[u]*w1[u][k]*Wsv[u][k][m]; then msg_v atomics
  if (!SZERO) {
    float q[64];
#pragma unroll
    for (int m = 0; m < 64; ++m) q[m] = 0.f;
    const float* srowp = s + (size_t)src * 64;
#pragma unroll 1
    for (int u = 0; u < 64; ++u) {
      float su = srowp[u];
      const float4* c0 = (const float4*)(sf2 + u * 128);   // col 2u ; col 2u+1 at +16
      float w10 = 0.f, w11 = 0.f;
#pragma unroll
      for (int j4 = 0; j4 < 16; ++j4) {
        float4 A4 = c0[j4];
        float4 B4 = c0[j4 + 16];
        float h0 = hid[4 * j4 + 0], h1 = hid[4 * j4 + 1], h2_ = hid[4 * j4 + 2], h3 = hid[4 * j4 + 3];
        w10 += h0 * A4.x + h1 * A4.y + h2_ * A4.z + h3 * A4.w;
        w11 += h0 * B4.x + h1 * B4.y + h2_ * B4.z + h3 * B4.w;
      }
      float t0 = su * w10, t1 = su * w11;
      const float4* wv = (const float4*)(Wsv + u * 64);    // [u][k][m]
#pragma unroll
      for (int m4 = 0; m4 < 8; ++m4) {
        float4 W0 = wv[m4];
        float4 W1 = wv[m4 + 8];
        q[4 * m4 + 0] += t0 * W0.x; q[4 * m4 + 1] += t0 * W0.y;
        q[4 * m4 + 2] += t0 * W0.z; q[4 * m4 + 3] += t0 * W0.w;
        q[32 + 4 * m4 + 0] += t1 * W1.x; q[32 + 4 * m4 + 1] += t1 * W1.y;
        q[32 + 4 * m4 + 2] += t1 * W1.z; q[32 + 4 * m4 + 3] += t1 * W1.w;
      }
    }
    float* av = agg_v + (size_t)dst * 96;
#pragma unroll
    for (int m = 0; m < 32; ++m) {
      atomicAdd(av + 3 * m + 0, (q[m] * a00 + q[32 + m] * a10) * INV_SQRT_NN);
      atomicAdd(av + 3 * m + 1, (q[m] * a01 + q[32 + m] * a11) * INV_SQRT_NN);
      atomicAdd(av + 3 * m + 2, (q[m] * a02 + q[32 + m] * a12) * INV_SQRT_NN);
    }
  }

  // ---- Pass B: msg_s[m] = sum_{u,k} d[u][k]*w2[u][k]*Wvs[u][k][m]
  float msg[96];
#pragma unroll
  for (int m = 0; m < 96; ++m) msg[m] = 0.f;
  const float* vrowp = v + (size_t)src * 96;
#pragma unroll 1
  for (int u = 0; u < 32; ++u) {
    float v0 = vrowp[3 * u + 0], v1 = vrowp[3 * u + 1], v2 = vrowp[3 * u + 2];
    float d0 = v0 * a00 + v1 * a01 + v2 * a02;
    float d1 = v0 * a10 + v1 * a11 + v2 * a12;
    const float4* c0 = (const float4*)(sf2 + 8192 + u * 128);  // col 128+2u ; +1 at +16
    float w20 = 0.f, w21 = 0.f;
#pragma unroll
    for (int j4 = 0; j4 < 16; ++j4) {
      float4 A4 = c0[j4];
      float4 B4 = c0[j4 + 16];
      float h0 = hid[4 * j4 + 0], h1 = hid[4 * j4 + 1], h2_ = hid[4 * j4 + 2], h3 = hid[4 * j4 + 3];
      w20 += h0 * A4.x + h1 * A4.y + h2_ * A4.z + h3 * A4.w;
      w21 += h0 * B4.x + h1 * B4.y + h2_ * B4.z + h3 * B4.w;
    }
    float g0 = d0 * w20, g1 = d1 * w21;
    const float4* wv = (const float4*)(Wvs + u * 192);         // [u][k][m]
#pragma unroll
    for (int m4 = 0; m4 < 24; ++m4) {
      float4 A4 = wv[m4];
      float4 B4 = wv[m4 + 24];
      msg[4 * m4 + 0] += g0 * A4.x + g1 * B4.x;
      msg[4 * m4 + 1] += g0 * A4.y + g1 * B4.y;
      msg[4 * m4 + 2] += g0 * A4.z + g1 * B4.z;
      msg[4 * m4 + 3] += g0 * A4.w + g1 * B4.w;
    }
  }
  float* asr = agg_s + (size_t)dst * 96;
#pragma unroll
  for (int m = 0; m < 96; ++m) atomicAdd(asr + m, msg[m] * INV_SQRT_NN);
}

// ---------------- node update kernel (one block per node) ----------------
__global__ __launch_bounds__(128) void k_node(
    float* __restrict__ s, float* __restrict__ sold, float* __restrict__ v,
    float* __restrict__ vold, const float* __restrict__ aggs, const float* __restrict__ aggv,
    const float* __restrict__ Amat, const float* __restrict__ Bmat,
    const float* __restrict__ Ws, const float* __restrict__ Wv,
    const float* __restrict__ Wproj, const int* __restrict__ nattr,
    const float* __restrict__ hArr, const float* __restrict__ mixArr, int layer,
    float* __restrict__ xout, int N) {
  int n = blockIdx.x;
  int t = threadIdx.x;
  __shared__ float srow[64];
  __shared__ float vrow[96];
  __shared__ float gateS[32];
  __shared__ float vnewS[96];
  if (t < 64) srow[t] = s[(size_t)n * 64 + t];
  if (t < 96) vrow[t] = v[(size_t)n * 96 + t];
  __syncthreads();
  int type = nattr[n];
  float hv = hArr[layer];
  float h2 = hv * hv;
  float mx = mixArr[layer];
  float cs = 0.f;
  if (t < 96) {
    cs = aggs[(size_t)n * 96 + t];   // already normalized by 1/sqrt(NN)
    const float* Ac = Amat + (size_t)type * 64 * 96 + t;
#pragma unroll 8
    for (int u = 0; u < 64; ++u) cs += srow[u] * Ac[u * 96];
  }
  if (t >= 64 && t < 96) gateS[t - 64] = 1.0f / (1.0f + __expf(-cs));
  __syncthreads();
  if (t < 64) {
    float gs = cs * (1.0f / (1.0f + __expf(-cs)));
    float sis = 0.f;
#pragma unroll 8
    for (int u = 0; u < 64; ++u) sis += srow[u] * Ws[u * 64 + t];
    float scur = srow[t];
    float sprev = sold[(size_t)n * 64 + t];
    float snew = 2.f * scur - sprev + h2 * (mx * gs + (mx - 1.f) * sis);
    sold[(size_t)n * 64 + t] = scur;
    s[(size_t)n * 64 + t] = snew;
  }
  if (t < 96) {
    int vch = t / 3, c = t - vch * 3;
    float cv = aggv[(size_t)n * 96 + t];
    const float* Bc = Bmat + (size_t)type * 1024 + vch;
    float scv = 0.f, siv = 0.f;
#pragma unroll 8
    for (int u = 0; u < 32; ++u) {
      float vu = vrow[u * 3 + c];
      scv += vu * Bc[u * 32];
      siv += vu * Wv[u * 32 + vch];
    }
    cv += scv;
    float gv = cv * gateS[vch];
    float vcur = vrow[t];
    float vprev = vold[(size_t)n * 96 + t];
    float vnew = 2.f * vcur - vprev + h2 * (mx * gv + (mx - 1.f) * siv);
    vold[(size_t)n * 96 + t] = vcur;
    v[(size_t)n * 96 + t] = vnew;
    vnewS[t] = vnew;
  }
  __syncthreads();
  if (t < 6) {
    int i = t / 3, c = t - i * 3;
    float acc = 0.f;
#pragma unroll
    for (int vo = 0; vo < 32; ++vo) acc += vnewS[vo * 3 + c] * Wproj[vo * 2 + i];
    xout[(size_t)n * 6 + t] = acc;
  }
}

extern "C" void kernel_launch(void* const* d_in, const int* in_sizes, int n_in,
                              void* d_out, int out_size, void* d_ws, size_t ws_size,
                              hipStream_t stream) {
  const float* x = (const float*)d_in[0];
  const float* emb = (const float*)d_in[1];
  const float* Wup = (const float*)d_in[2];
  const float* Wproj = (const float*)d_in[3];
  const float* fc1 = (const float*)d_in[4];
  const float* b1 = (const float*)d_in[5];
  const float* fc2 = (const float*)d_in[6];
  const float* Wsv = (const float*)d_in[7];
  const float* Wvs = (const float*)d_in[8];
  const float* Wscs = (const float*)d_in[9];
  const float* Wscv = (const float*)d_in[10];
  const float* Ws = (const float*)d_in[11];
  const float* Wv = (const float*)d_in[12];
  const float* hArr = (const float*)d_in[13];
  const float* mixArr = (const float*)d_in[14];
  const int* nattr = (const int*)d_in[15];
  const int* esrc = (const int*)d_in[16];
  const int* edst = (const int*)d_in[17];

  const int N = in_sizes[0] / 6;
  const int E = in_sizes[16];

  float* ws = (float*)d_ws;
  float* sbuf = ws;                               // N*64
  float* sold = sbuf + (size_t)N * 64;            // N*64
  float* vbuf = sold + (size_t)N * 64;            // N*96
  float* vold = vbuf + (size_t)N * 96;            // N*96
  float* aggs = vold + (size_t)N * 96;            // N*96
  float* aggv = aggs + (size_t)N * 96;            // N*96
  float* xcur = aggv + (size_t)N * 96;            // N*6
  float* Amat = xcur + (size_t)N * 6;             // L*10*64*96
  float* Bmat = Amat + (size_t)cL * cNT * 64 * 96;  // L*10*32*32
  float* fc2T = Bmat + (size_t)cL * cNT * 32 * 32;  // L*12288
  float* fc1T = fc2T + (size_t)cL * 12288;          // L*1024

  // init: s = s_old = 0, v = v_old = uplift(x), xcur = x
  hipMemsetAsync(sbuf, 0, sizeof(float) * (size_t)N * 128, stream);
  k_init<<<(N * 32 + 255) / 256, 256, 0, stream>>>(x, Wup, vbuf, vold, xcur, N);
  k_precompA<<<(cL * cNT * 64 * 96 + 255) / 256, 256, 0, stream>>>(emb, Wscs, Amat);
  k_precompB<<<(cL * cNT * 32 * 32 + 255) / 256, 256, 0, stream>>>(emb, Wscv, Bmat);
  k_transpose_fc<<<(cL * 12288 + 255) / 256, 256, 0, stream>>>(fc1, fc2, fc1T, fc2T);

  for (int l = 0; l < cL; ++l) {
    hipMemsetAsync(aggs, 0, sizeof(float) * (size_t)N * 192, stream);  // aggs + aggv
    if (l == 0)
      k_edge<true><<<(E + 255) / 256, 256, 0, stream>>>(
          xcur, sbuf, vbuf, esrc, edst, fc1T + l * 1024, b1 + l * 64, fc2T + l * 12288,
          Wsv + l * 4096, Wvs + l * 6144, aggs, aggv, E);
    else
      k_edge<false><<<(E + 255) / 256, 256, 0, stream>>>(
          xcur, sbuf, vbuf, esrc, edst, fc1T + l * 1024, b1 + l * 64, fc2T + l * 12288,
          Wsv + l * 4096, Wvs + l * 6144, aggs, aggv, E);
    float* xout = (l == cL - 1) ? (float*)d_out : xcur;
    k_node<<<N, 128, 0, stream>>>(sbuf, sold, vbuf, vold, aggs, aggv,
                                  Amat + (size_t)l * cNT * 64 * 96,
                                  Bmat + (size_t)l * cNT * 1024, Ws + l * 4096,
                                  Wv + l * 1024, Wproj, nattr, hArr, mixArr, l, xout, N);
  }
}

// Round 2
// 2559.018 us; speedup vs baseline: 4.6128x; 4.6128x over previous
//
#include <hip/hip_runtime.h>
#include <math.h>

constexpr int cNS = 64, cNV = 32, cNB = 8, cL = 4, cEMB = 32, cNT = 10;
constexpr float PI_F = 3.14159265358979323846f;
constexpr float INV_SQRT_NN = 0.17677669529663687f;   // 1/sqrt(32)
constexpr float BESSEL_C = 2.3094010767585034f;       // sqrt(2/3)*sqrt(8)
constexpr float SQRT3 = 1.7320508075688772f;

// ---------------- precompute kernels ----------------

__global__ void k_precompA(const float* __restrict__ emb, const float* __restrict__ Wss,
                           float* __restrict__ A) {
  int idx = blockIdx.x * 256 + threadIdx.x;
  if (idx >= cL * cNT * 64 * 96) return;
  int m = idx % 96;
  int u = (idx / 96) % 64;
  int t = (idx / (96 * 64)) % cNT;
  int l = idx / (96 * 64 * cNT);
  float acc = 0.f;
#pragma unroll
  for (int e = 0; e < 32; ++e)
    acc += emb[t * 32 + e] * Wss[((size_t)(l * 64 + u) * 32 + e) * 96 + m];
  A[idx] = acc;
}

__global__ void k_precompB(const float* __restrict__ emb, const float* __restrict__ Wsv_,
                           float* __restrict__ B) {
  int idx = blockIdx.x * 256 + threadIdx.x;
  if (idx >= cL * cNT * 32 * 32) return;
  int vo = idx % 32;
  int u = (idx / 32) % 32;
  int t = (idx / 1024) % cNT;
  int l = idx / (1024 * cNT);
  float acc = 0.f;
#pragma unroll
  for (int e = 0; e < 32; ++e)
    acc += emb[t * 32 + e] * Wsv_[((size_t)(l * 32 + u) * 32 + e) * 32 + vo];
  B[idx] = acc;
}

__global__ void k_transpose_fc(const float* __restrict__ fc1, const float* __restrict__ fc2,
                               float* __restrict__ fc1T, float* __restrict__ fc2T) {
  int idx = blockIdx.x * 256 + threadIdx.x;
  if (idx < cL * 12288) {
    int l = idx / 12288, p = idx % 12288;
    int o = p / 64, j = p % 64;
    fc2T[idx] = fc2[l * 12288 + j * 192 + o];
  }
  if (idx < cL * 1024) {
    int l = idx / 1024, p = idx % 1024;
    int j = p / 16, t = p % 16;
    fc1T[idx] = fc1[l * 1024 + t * 64 + j];
  }
}

__global__ void k_init(const float* __restrict__ x, const float* __restrict__ Wup,
                       float* __restrict__ v, float* __restrict__ v_old,
                       float* __restrict__ xcur, int N) {
  int idx = blockIdx.x * 256 + threadIdx.x;
  if (idx >= N * 32) return;
  int n = idx >> 5, vc = idx & 31;
  float w0 = Wup[vc], w1 = Wup[32 + vc];
#pragma unroll
  for (int c = 0; c < 3; ++c) {
    float val = x[n * 6 + c] * w0 + x[n * 6 + 3 + c] * w1;
    v[idx * 3 + c] = val;
    v_old[idx * 3 + c] = val;
  }
  if (vc < 6) xcur[n * 6 + vc] = x[n * 6 + vc];
}

// ---------------- CSR build (once per launch; graph is static across layers) --------

__global__ void k_zero_i(int* __restrict__ p, int n) {
  int i = blockIdx.x * 256 + threadIdx.x;
  if (i < n) p[i] = 0;
}

__global__ void k_hist(const int* __restrict__ edst, int* __restrict__ deg, int E) {
  int e = blockIdx.x * 256 + threadIdx.x;
  if (e < E) atomicAdd(&deg[edst[e]], 1);
}

// single-block exclusive scan over N counters -> row_ptr[0..N], cursor copy
__global__ __launch_bounds__(1024) void k_scan(const int* __restrict__ deg,
                                               int* __restrict__ row_ptr,
                                               int* __restrict__ cursor, int N) {
  __shared__ int part[1024];
  int t = threadIdx.x;
  int chunk = (N + 1023) / 1024;
  int base = t * chunk;
  int sum = 0;
  for (int i = 0; i < chunk; ++i) {
    int idx = base + i;
    if (idx < N) sum += deg[idx];
  }
  part[t] = sum;
  __syncthreads();
  for (int off = 1; off < 1024; off <<= 1) {
    int val = (t >= off) ? part[t - off] : 0;
    __syncthreads();
    part[t] += val;
    __syncthreads();
  }
  int run = (t > 0) ? part[t - 1] : 0;
  for (int i = 0; i < chunk; ++i) {
    int idx = base + i;
    if (idx < N) {
      row_ptr[idx] = run;
      cursor[idx] = run;
      run += deg[idx];
    }
  }
  if (t == 1023) row_ptr[N] = part[1023];
}

__global__ void k_scatter(const int* __restrict__ edst, int* __restrict__ cursor,
                          int* __restrict__ pos_of_e, int E) {
  int e = blockIdx.x * 256 + threadIdx.x;
  if (e < E) pos_of_e[e] = atomicAdd(&cursor[edst[e]], 1);
}

// ---------------- edge kernel, gather variant: stores msg row at sorted pos --------
// row layout (stride 192): [0..95]=msg_s, [96..191]=msg_v (m*3+c). SZERO: stride 96, msg_s only.
template <bool SZERO>
__global__ __launch_bounds__(256, 2) void k_edge_g(
    const float* __restrict__ xcur, const float* __restrict__ s, const float* __restrict__ v,
    const int* __restrict__ esrc, const int* __restrict__ edst,
    const int* __restrict__ pos_of_e,
    const float* __restrict__ fc1T, const float* __restrict__ b1,
    const float* __restrict__ fc2T, const float* __restrict__ Wsv,
    const float* __restrict__ Wvs, float* __restrict__ msgbuf, int E) {
  __shared__ float sf1[1024];    // fc1T  [j][t]
  __shared__ float sb1v[64];
  __shared__ float sf2[12288];   // fc2T  [o][j]
  for (int i = threadIdx.x; i < 1024; i += 256) sf1[i] = fc1T[i];
  if (threadIdx.x < 64) sb1v[threadIdx.x] = b1[threadIdx.x];
  for (int i = threadIdx.x; i < 12288; i += 256) sf2[i] = fc2T[i];
  __syncthreads();

  int e = blockIdx.x * 256 + threadIdx.x;
  if (e >= E) return;
  int src = esrc[e], dst = edst[e];
  float* row = msgbuf + (size_t)pos_of_e[e] * (SZERO ? 96 : 192);

  float xsrc[6], xdst[6];
  {
    const float2* ps = (const float2*)(xcur + (size_t)src * 6);
    const float2* pd = (const float2*)(xcur + (size_t)dst * 6);
    float2 A0 = ps[0], A1 = ps[1], A2 = ps[2];
    float2 B0 = pd[0], B1 = pd[1], B2 = pd[2];
    xsrc[0] = A0.x; xsrc[1] = A0.y; xsrc[2] = A1.x; xsrc[3] = A1.y; xsrc[4] = A2.x; xsrc[5] = A2.y;
    xdst[0] = B0.x; xdst[1] = B0.y; xdst[2] = B1.x; xdst[3] = B1.y; xdst[4] = B2.x; xdst[5] = B2.y;
  }

  float f[16];
  float a00, a01, a02, a10, a11, a12;
#pragma unroll
  for (int i = 0; i < 2; ++i) {
    float vx = xsrc[3 * i + 0] - xdst[3 * i + 0];
    float vy = xsrc[3 * i + 1] - xdst[3 * i + 1];
    float vz = xsrc[3 * i + 2] - xdst[3 * i + 2];
    float r2 = vx * vx + vy * vy + vz * vz;
    float r = sqrtf(r2);
    float invr = 1.0f / r;
    float th = (PI_F / 3.0f) * r;
    float s1, c1;
    __sincosf(th, &s1, &c1);
    float twc = 2.0f * c1;
    float snm = 0.f, sn = s1;
    float fc = BESSEL_C * invr;
#pragma unroll
    for (int nn = 0; nn < 8; ++nn) {
      f[8 * i + nn] = fc * sn;
      float nx = twc * sn - snm;
      snm = sn;
      sn = nx;
    }
    float uu = (2.0f / 3.0f) * r - 2.0f;
    float cut;
    if (uu > 0.f) cut = 0.f;
    else if (uu < -1.f) cut = 1.f;
    else cut = (1.0f - __cosf(PI_F * uu)) * 0.5f;
    float sc = cut * SQRT3 * invr;
    if (i == 0) { a00 = vx * sc; a01 = vy * sc; a02 = vz * sc; }
    else        { a10 = vx * sc; a11 = vy * sc; a12 = vz * sc; }
  }

  // hidden = silu(f @ fc1 + b1)
  float hid[64];
#pragma unroll
  for (int j = 0; j < 64; ++j) {
    const float4* rw = (const float4*)(sf1 + j * 16);
    float4 w0 = rw[0], w1 = rw[1], w2 = rw[2], w3 = rw[3];
    float acc = sb1v[j];
    acc += f[0] * w0.x + f[1] * w0.y + f[2] * w0.z + f[3] * w0.w;
    acc += f[4] * w1.x + f[5] * w1.y + f[6] * w1.z + f[7] * w1.w;
    acc += f[8] * w2.x + f[9] * w2.y + f[10] * w2.z + f[11] * w2.w;
    acc += f[12] * w3.x + f[13] * w3.y + f[14] * w3.z + f[15] * w3.w;
    hid[j] = acc * (1.0f / (1.0f + __expf(-acc)));
  }

  // ---- Pass A: q then msg_v -> row[96..191]
  if (!SZERO) {
    float q[64];
#pragma unroll
    for (int m = 0; m < 64; ++m) q[m] = 0.f;
    const float* srowp = s + (size_t)src * 64;
#pragma unroll 1
    for (int u = 0; u < 64; ++u) {
      float su = srowp[u];
      const float4* c0 = (const float4*)(sf2 + u * 128);
      float w10 = 0.f, w11 = 0.f;
#pragma unroll
      for (int j4 = 0; j4 < 16; ++j4) {
        float4 A4 = c0[j4];
        float4 B4 = c0[j4 + 16];
        float h0 = hid[4 * j4 + 0], h1 = hid[4 * j4 + 1], h2_ = hid[4 * j4 + 2], h3 = hid[4 * j4 + 3];
        w10 += h0 * A4.x + h1 * A4.y + h2_ * A4.z + h3 * A4.w;
        w11 += h0 * B4.x + h1 * B4.y + h2_ * B4.z + h3 * B4.w;
      }
      float t0 = su * w10, t1 = su * w11;
      const float4* wv = (const float4*)(Wsv + u * 64);
#pragma unroll
      for (int m4 = 0; m4 < 8; ++m4) {
        float4 W0 = wv[m4];
        float4 W1 = wv[m4 + 8];
        q[4 * m4 + 0] += t0 * W0.x; q[4 * m4 + 1] += t0 * W0.y;
        q[4 * m4 + 2] += t0 * W0.z; q[4 * m4 + 3] += t0 * W0.w;
        q[32 + 4 * m4 + 0] += t1 * W1.x; q[32 + 4 * m4 + 1] += t1 * W1.y;
        q[32 + 4 * m4 + 2] += t1 * W1.z; q[32 + 4 * m4 + 3] += t1 * W1.w;
      }
    }
    float vm[96];
#pragma unroll
    for (int m = 0; m < 32; ++m) {
      vm[3 * m + 0] = q[m] * a00 + q[32 + m] * a10;
      vm[3 * m + 1] = q[m] * a01 + q[32 + m] * a11;
      vm[3 * m + 2] = q[m] * a02 + q[32 + m] * a12;
    }
    float4* outv = (float4*)(row + 96);
#pragma unroll
    for (int i = 0; i < 24; ++i)
      outv[i] = make_float4(vm[4 * i], vm[4 * i + 1], vm[4 * i + 2], vm[4 * i + 3]);
  }

  // ---- Pass B: msg_s -> row[0..95]
  float msg[96];
#pragma unroll
  for (int m = 0; m < 96; ++m) msg[m] = 0.f;
  const float* vrowp = v + (size_t)src * 96;
#pragma unroll 1
  for (int u = 0; u < 32; ++u) {
    float v0 = vrowp[3 * u + 0], v1 = vrowp[3 * u + 1], v2 = vrowp[3 * u + 2];
    float d0 = v0 * a00 + v1 * a01 + v2 * a02;
    float d1 = v0 * a10 + v1 * a11 + v2 * a12;
    const float4* c0 = (const float4*)(sf2 + 8192 + u * 128);
    float w20 = 0.f, w21 = 0.f;
#pragma unroll
    for (int j4 = 0; j4 < 16; ++j4) {
      float4 A4 = c0[j4];
      float4 B4 = c0[j4 + 16];
      float h0 = hid[4 * j4 + 0], h1 = hid[4 * j4 + 1], h2_ = hid[4 * j4 + 2], h3 = hid[4 * j4 + 3];
      w20 += h0 * A4.x + h1 * A4.y + h2_ * A4.z + h3 * A4.w;
      w21 += h0 * B4.x + h1 * B4.y + h2_ * B4.z + h3 * B4.w;
    }
    float g0 = d0 * w20, g1 = d1 * w21;
    const float4* wv = (const float4*)(Wvs + u * 192);
#pragma unroll
    for (int m4 = 0; m4 < 24; ++m4) {
      float4 A4 = wv[m4];
      float4 B4 = wv[m4 + 24];
      msg[4 * m4 + 0] += g0 * A4.x + g1 * B4.x;
      msg[4 * m4 + 1] += g0 * A4.y + g1 * B4.y;
      msg[4 * m4 + 2] += g0 * A4.z + g1 * B4.z;
      msg[4 * m4 + 3] += g0 * A4.w + g1 * B4.w;
    }
  }
  float4* outs = (float4*)row;
#pragma unroll
  for (int i = 0; i < 24; ++i)
    outs[i] = make_float4(msg[4 * i], msg[4 * i + 1], msg[4 * i + 2], msg[4 * i + 3]);
}

// ---------------- fused gather + node update (block of 128 per node) ----------------
template <bool SZERO>
__global__ __launch_bounds__(128) void k_gnode(
    const float* __restrict__ msg, const int* __restrict__ row_ptr,
    float* __restrict__ s, float* __restrict__ sold, float* __restrict__ v,
    float* __restrict__ vold,
    const float* __restrict__ Amat, const float* __restrict__ Bmat,
    const float* __restrict__ Ws, const float* __restrict__ Wv,
    const float* __restrict__ Wproj, const int* __restrict__ nattr,
    const float* __restrict__ hArr, const float* __restrict__ mixArr, int layer,
    float* __restrict__ xout, int N) {
  int n = blockIdx.x;
  int t = threadIdx.x;
  __shared__ float agg[192];   // [0..95]=agg_s, [96..191]=agg_v
  __shared__ float srow[64];
  __shared__ float vrow[96];
  __shared__ float gateS[32];
  __shared__ float vnewS[96];
  int start = row_ptr[n], end = row_ptr[n + 1];
  if (SZERO) {
    if (t < 96) {
      float a0 = 0.f;
      for (int p = start; p < end; ++p) a0 += msg[(size_t)p * 96 + t];
      agg[t] = a0 * INV_SQRT_NN;
      agg[96 + t] = 0.f;
    }
  } else {
    float a0 = 0.f, a1 = 0.f;
    for (int p = start; p < end; ++p) {
      const float* rr = msg + (size_t)p * 192;
      a0 += rr[t];
      if (t < 64) a1 += rr[128 + t];
    }
    agg[t] = a0 * INV_SQRT_NN;
    if (t < 64) agg[128 + t] = a1 * INV_SQRT_NN;
  }
  if (t < 64) srow[t] = s[(size_t)n * 64 + t];
  if (t < 96) vrow[t] = v[(size_t)n * 96 + t];
  __syncthreads();
  int type = nattr[n];
  float hv = hArr[layer];
  float h2 = hv * hv;
  float mx = mixArr[layer];
  float cs = 0.f;
  if (t < 96) {
    cs = agg[t];
    const float* Ac = Amat + (size_t)type * 64 * 96 + t;
#pragma unroll 8
    for (int u = 0; u < 64; ++u) cs += srow[u] * Ac[u * 96];
  }
  if (t >= 64 && t < 96) gateS[t - 64] = 1.0f / (1.0f + __expf(-cs));
  __syncthreads();
  if (t < 64) {
    float gs = cs * (1.0f / (1.0f + __expf(-cs)));
    float sis = 0.f;
#pragma unroll 8
    for (int u = 0; u < 64; ++u) sis += srow[u] * Ws[u * 64 + t];
    float scur = srow[t];
    float sprev = sold[(size_t)n * 64 + t];
    float snew = 2.f * scur - sprev + h2 * (mx * gs + (mx - 1.f) * sis);
    sold[(size_t)n * 64 + t] = scur;
    s[(size_t)n * 64 + t] = snew;
  }
  if (t < 96) {
    int vch = t / 3, c = t - vch * 3;
    float cv = agg[96 + t];
    const float* Bc = Bmat + (size_t)type * 1024 + vch;
    float scv = 0.f, siv = 0.f;
#pragma unroll 8
    for (int u = 0; u < 32; ++u) {
      float vu = vrow[u * 3 + c];
      scv += vu * Bc[u * 32];
      siv += vu * Wv[u * 32 + vch];
    }
    cv += scv;
    float gv = cv * gateS[vch];
    float vcur = vrow[t];
    float vprev = vold[(size_t)n * 96 + t];
    float vnew = 2.f * vcur - vprev + h2 * (mx * gv + (mx - 1.f) * siv);
    vold[(size_t)n * 96 + t] = vcur;
    v[(size_t)n * 96 + t] = vnew;
    vnewS[t] = vnew;
  }
  __syncthreads();
  if (t < 6) {
    int i = t / 3, c = t - i * 3;
    float acc = 0.f;
#pragma unroll
    for (int vo = 0; vo < 32; ++vo) acc += vnewS[vo * 3 + c] * Wproj[vo * 2 + i];
    xout[(size_t)n * 6 + t] = acc;
  }
}

// ---------------- fallback: round-1 atomic path ----------------
template <bool SZERO>
__global__ __launch_bounds__(256, 2) void k_edge(
    const float* __restrict__ xcur, const float* __restrict__ s, const float* __restrict__ v,
    const int* __restrict__ esrc, const int* __restrict__ edst,
    const float* __restrict__ fc1T, const float* __restrict__ b1,
    const float* __restrict__ fc2T, const float* __restrict__ Wsv,
    const float* __restrict__ Wvs, float* __restrict__ agg_s, float* __restrict__ agg_v,
    int E) {
  __shared__ float sf1[1024];
  __shared__ float sb1v[64];
  __shared__ float sf2[12288];
  for (int i = threadIdx.x; i < 1024; i += 256) sf1[i] = fc1T[i];
  if (threadIdx.x < 64) sb1v[threadIdx.x] = b1[threadIdx.x];
  for (int i = threadIdx.x; i < 12288; i += 256) sf2[i] = fc2T[i];
  __syncthreads();

  int e = blockIdx.x * 256 + threadIdx.x;
  if (e >= E) return;
  int src = esrc[e], dst = edst[e];

  float xsrc[6], xdst[6];
  {
    const float2* ps = (const float2*)(xcur + (size_t)src * 6);
    const float2* pd = (const float2*)(xcur + (size_t)dst * 6);
    float2 A0 = ps[0], A1 = ps[1], A2 = ps[2];
    float2 B0 = pd[0], B1 = pd[1], B2 = pd[2];
    xsrc[0] = A0.x; xsrc[1] = A0.y; xsrc[2] = A1.x; xsrc[3] = A1.y; xsrc[4] = A2.x; xsrc[5] = A2.y;
    xdst[0] = B0.x; xdst[1] = B0.y; xdst[2] = B1.x; xdst[3] = B1.y; xdst[4] = B2.x; xdst[5] = B2.y;
  }

  float f[16];
  float a00, a01, a02, a10, a11, a12;
#pragma unroll
  for (int i = 0; i < 2; ++i) {
    float vx = xsrc[3 * i + 0] - xdst[3 * i + 0];
    float vy = xsrc[3 * i + 1] - xdst[3 * i + 1];
    float vz = xsrc[3 * i + 2] - xdst[3 * i + 2];
    float r2 = vx * vx + vy * vy + vz * vz;
    float r = sqrtf(r2);
    float invr = 1.0f / r;
    float th = (PI_F / 3.0f) * r;
    float s1, c1;
    __sincosf(th, &s1, &c1);
    float twc = 2.0f * c1;
    float snm = 0.f, sn = s1;
    float fc = BESSEL_C * invr;
#pragma unroll
    for (int nn = 0; nn < 8; ++nn) {
      f[8 * i + nn] = fc * sn;
      float nx = twc * sn - snm;
      snm = sn;
      sn = nx;
    }
    float uu = (2.0f / 3.0f) * r - 2.0f;
    float cut;
    if (uu > 0.f) cut = 0.f;
    else if (uu < -1.f) cut = 1.f;
    else cut = (1.0f - __cosf(PI_F * uu)) * 0.5f;
    float sc = cut * SQRT3 * invr;
    if (i == 0) { a00 = vx * sc; a01 = vy * sc; a02 = vz * sc; }
    else        { a10 = vx * sc; a11 = vy * sc; a12 = vz * sc; }
  }

  float hid[64];
#pragma unroll
  for (int j = 0; j < 64; ++j) {
    const float4* rw = (const float4*)(sf1 + j * 16);
    float4 w0 = rw[0], w1 = rw[1], w2 = rw[2], w3 = rw[3];
    float acc = sb1v[j];
    acc += f[0] * w0.x + f[1] * w0.y + f[2] * w0.z + f[3] * w0.w;
    acc += f[4] * w1.x + f[5] * w1.y + f[6] * w1.z + f[7] * w1.w;
    acc += f[8] * w2.x + f[9] * w2.y + f[10] * w2.z + f[11] * w2.w;
    acc += f[12] * w3.x + f[13] * w3.y + f[14] * w3.z + f[15] * w3.w;
    hid[j] = acc * (1.0f / (1.0f + __expf(-acc)));
  }

  if (!SZERO) {
    float q[64];
#pragma unroll
    for (int m = 0; m < 64; ++m) q[m] = 0.f;
    const float* srowp = s + (size_t)src * 64;
#pragma unroll 1
    for (int u = 0; u < 64; ++u) {
      float su = srowp[u];
      const float4* c0 = (const float4*)(sf2 + u * 128);
      float w10 = 0.f, w11 = 0.f;
#pragma unroll
      for (int j4 = 0; j4 < 16; ++j4) {
        float4 A4 = c0[j4];
        float4 B4 = c0[j4 + 16];
        float h0 = hid[4 * j4 + 0], h1 = hid[4 * j4 + 1], h2_ = hid[4 * j4 + 2], h3 = hid[4 * j4 + 3];
        w10 += h0 * A4.x + h1 * A4.y + h2_ * A4.z + h3 * A4.w;
        w11 += h0 * B4.x + h1 * B4.y + h2_ * B4.z + h3 * B4.w;
      }
      float t0 = su * w10, t1 = su * w11;
      const float4* wv = (const float4*)(Wsv + u * 64);
#pragma unroll
      for (int m4 = 0; m4 < 8; ++m4) {
        float4 W0 = wv[m4];
        float4 W1 = wv[m4 + 8];
        q[4 * m4 + 0] += t0 * W0.x; q[4 * m4 + 1] += t0 * W0.y;
        q[4 * m4 + 2] += t0 * W0.z; q[4 * m4 + 3] += t0 * W0.w;
        q[32 + 4 * m4 + 0] += t1 * W1.x; q[32 + 4 * m4 + 1] += t1 * W1.y;
        q[32 + 4 * m4 + 2] += t1 * W1.z; q[32 + 4 * m4 + 3] += t1 * W1.w;
      }
    }
    float* av = agg_v + (size_t)dst * 96;
#pragma unroll
    for (int m = 0; m < 32; ++m) {
      atomicAdd(av + 3 * m + 0, (q[m] * a00 + q[32 + m] * a10) * INV_SQRT_NN);
      atomicAdd(av + 3 * m + 1, (q[m] * a01 + q[32 + m] * a11) * INV_SQRT_NN);
      atomicAdd(av + 3 * m + 2, (q[m] * a02 + q[32 + m] * a12) * INV_SQRT_NN);
    }
  }

  float msg[96];
#pragma unroll
  for (int m = 0; m < 96; ++m) msg[m] = 0.f;
  const float* vrowp = v + (size_t)src * 96;
#pragma unroll 1
  for (int u = 0; u < 32; ++u) {
    float v0 = vrowp[3 * u + 0], v1 = vrowp[3 * u + 1], v2 = vrowp[3 * u + 2];
    float d0 = v0 * a00 + v1 * a01 + v2 * a02;
    float d1 = v0 * a10 + v1 * a11 + v2 * a12;
    const float4* c0 = (const float4*)(sf2 + 8192 + u * 128);
    float w20 = 0.f, w21 = 0.f;
#pragma unroll
    for (int j4 = 0; j4 < 16; ++j4) {
      float4 A4 = c0[j4];
      float4 B4 = c0[j4 + 16];
      float h0 = hid[4 * j4 + 0], h1 = hid[4 * j4 + 1], h2_ = hid[4 * j4 + 2], h3 = hid[4 * j4 + 3];
      w20 += h0 * A4.x + h1 * A4.y + h2_ * A4.z + h3 * A4.w;
      w21 += h0 * B4.x + h1 * B4.y + h2_ * B4.z + h3 * B4.w;
    }
    float g0 = d0 * w20, g1 = d1 * w21;
    const float4* wv = (const float4*)(Wvs + u * 192);
#pragma unroll
    for (int m4 = 0; m4 < 24; ++m4) {
      float4 A4 = wv[m4];
      float4 B4 = wv[m4 + 24];
      msg[4 * m4 + 0] += g0 * A4.x + g1 * B4.x;
      msg[4 * m4 + 1] += g0 * A4.y + g1 * B4.y;
      msg[4 * m4 + 2] += g0 * A4.z + g1 * B4.z;
      msg[4 * m4 + 3] += g0 * A4.w + g1 * B4.w;
    }
  }
  float* asr = agg_s + (size_t)dst * 96;
#pragma unroll
  for (int m = 0; m < 96; ++m) atomicAdd(asr + m, msg[m] * INV_SQRT_NN);
}

__global__ __launch_bounds__(128) void k_node(
    float* __restrict__ s, float* __restrict__ sold, float* __restrict__ v,
    float* __restrict__ vold, const float* __restrict__ aggs, const float* __restrict__ aggv,
    const float* __restrict__ Amat, const float* __restrict__ Bmat,
    const float* __restrict__ Ws, const float* __restrict__ Wv,
    const float* __restrict__ Wproj, const int* __restrict__ nattr,
    const float* __restrict__ hArr, const float* __restrict__ mixArr, int layer,
    float* __restrict__ xout, int N) {
  int n = blockIdx.x;
  int t = threadIdx.x;
  __shared__ float srow[64];
  __shared__ float vrow[96];
  __shared__ float gateS[32];
  __shared__ float vnewS[96];
  if (t < 64) srow[t] = s[(size_t)n * 64 + t];
  if (t < 96) vrow[t] = v[(size_t)n * 96 + t];
  __syncthreads();
  int type = nattr[n];
  float hv = hArr[layer];
  float h2 = hv * hv;
  float mx = mixArr[layer];
  float cs = 0.f;
  if (t < 96) {
    cs = aggs[(size_t)n * 96 + t];
    const float* Ac = Amat + (size_t)type * 64 * 96 + t;
#pragma unroll 8
    for (int u = 0; u < 64; ++u) cs += srow[u] * Ac[u * 96];
  }
  if (t >= 64 && t < 96) gateS[t - 64] = 1.0f / (1.0f + __expf(-cs));
  __syncthreads();
  if (t < 64) {
    float gs = cs * (1.0f / (1.0f + __expf(-cs)));
    float sis = 0.f;
#pragma unroll 8
    for (int u = 0; u < 64; ++u) sis += srow[u] * Ws[u * 64 + t];
    float scur = srow[t];
    float sprev = sold[(size_t)n * 64 + t];
    float snew = 2.f * scur - sprev + h2 * (mx * gs + (mx - 1.f) * sis);
    sold[(size_t)n * 64 + t] = scur;
    s[(size_t)n * 64 + t] = snew;
  }
  if (t < 96) {
    int vch = t / 3, c = t - vch * 3;
    float cv = aggv[(size_t)n * 96 + t];
    const float* Bc = Bmat + (size_t)type * 1024 + vch;
    float scv = 0.f, siv = 0.f;
#pragma unroll 8
    for (int u = 0; u < 32; ++u) {
      float vu = vrow[u * 3 + c];
      scv += vu * Bc[u * 32];
      siv += vu * Wv[u * 32 + vch];
    }
    cv += scv;
    float gv = cv * gateS[vch];
    float vcur = vrow[t];
    float vprev = vold[(size_t)n * 96 + t];
    float vnew = 2.f * vcur - vprev + h2 * (mx * gv + (mx - 1.f) * siv);
    vold[(size_t)n * 96 + t] = vcur;
    v[(size_t)n * 96 + t] = vnew;
    vnewS[t] = vnew;
  }
  __syncthreads();
  if (t < 6) {
    int i = t / 3, c = t - i * 3;
    float acc = 0.f;
#pragma unroll
    for (int vo = 0; vo < 32; ++vo) acc += vnewS[vo * 3 + c] * Wproj[vo * 2 + i];
    xout[(size_t)n * 6 + t] = acc;
  }
}

extern "C" void kernel_launch(void* const* d_in, const int* in_sizes, int n_in,
                              void* d_out, int out_size, void* d_ws, size_t ws_size,
                              hipStream_t stream) {
  const float* x = (const float*)d_in[0];
  const float* emb = (const float*)d_in[1];
  const float* Wup = (const float*)d_in[2];
  const float* Wproj = (const float*)d_in[3];
  const float* fc1 = (const float*)d_in[4];
  const float* b1 = (const float*)d_in[5];
  const float* fc2 = (const float*)d_in[6];
  const float* Wsv = (const float*)d_in[7];
  const float* Wvs = (const float*)d_in[8];
  const float* Wscs = (const float*)d_in[9];
  const float* Wscv = (const float*)d_in[10];
  const float* Ws = (const float*)d_in[11];
  const float* Wv = (const float*)d_in[12];
  const float* hArr = (const float*)d_in[13];
  const float* mixArr = (const float*)d_in[14];
  const int* nattr = (const int*)d_in[15];
  const int* esrc = (const int*)d_in[16];
  const int* edst = (const int*)d_in[17];

  const int N = in_sizes[0] / 6;
  const int E = in_sizes[16];

  float* ws = (float*)d_ws;
  size_t off = 0;
  auto alloc = [&](size_t nf) {
    float* p = ws + off;
    off += (nf + 3) & ~(size_t)3;
    return p;
  };
  float* sbuf = alloc((size_t)N * 64);
  float* sold = alloc((size_t)N * 64);
  float* vbuf = alloc((size_t)N * 96);
  float* vold = alloc((size_t)N * 96);
  float* xcur = alloc((size_t)N * 6);
  float* Amat = alloc((size_t)cL * cNT * 64 * 96);
  float* Bmat = alloc((size_t)cL * cNT * 32 * 32);
  float* fc2T = alloc((size_t)cL * 12288);
  float* fc1T = alloc((size_t)cL * 1024);
  size_t base_off = off;

  // gather-path extra
  int* deg = (int*)(ws + base_off);
  int* row_ptr = deg + (N + 4);
  int* cursor = row_ptr + (N + 4);
  int* pos_of_e = cursor + (N + 4);
  size_t msg_off = base_off + ((size_t)(3 * (N + 4) + E + 3) & ~(size_t)3);
  float* msgbuf = ws + msg_off;
  size_t need_gather = (msg_off + (size_t)E * 192 + 8) * sizeof(float);
  bool use_gather = ws_size >= need_gather;

  // common init
  hipMemsetAsync(sbuf, 0, sizeof(float) * (size_t)N * 128, stream);  // sbuf + sold
  k_init<<<(N * 32 + 255) / 256, 256, 0, stream>>>(x, Wup, vbuf, vold, xcur, N);
  k_precompA<<<(cL * cNT * 64 * 96 + 255) / 256, 256, 0, stream>>>(emb, Wscs, Amat);
  k_precompB<<<(cL * cNT * 32 * 32 + 255) / 256, 256, 0, stream>>>(emb, Wscv, Bmat);
  k_transpose_fc<<<(cL * 12288 + 255) / 256, 256, 0, stream>>>(fc1, fc2, fc1T, fc2T);

  if (use_gather) {
    // CSR build (graph static across layers)
    k_zero_i<<<(N + 255) / 256, 256, 0, stream>>>(deg, N);
    k_hist<<<(E + 255) / 256, 256, 0, stream>>>(edst, deg, E);
    k_scan<<<1, 1024, 0, stream>>>(deg, row_ptr, cursor, N);
    k_scatter<<<(E + 255) / 256, 256, 0, stream>>>(edst, cursor, pos_of_e, E);

    for (int l = 0; l < cL; ++l) {
      if (l == 0)
        k_edge_g<true><<<(E + 255) / 256, 256, 0, stream>>>(
            xcur, sbuf, vbuf, esrc, edst, pos_of_e, fc1T + l * 1024, b1 + l * 64,
            fc2T + l * 12288, Wsv + l * 4096, Wvs + l * 6144, msgbuf, E);
      else
        k_edge_g<false><<<(E + 255) / 256, 256, 0, stream>>>(
            xcur, sbuf, vbuf, esrc, edst, pos_of_e, fc1T + l * 1024, b1 + l * 64,
            fc2T + l * 12288, Wsv + l * 4096, Wvs + l * 6144, msgbuf, E);
      float* xout = (l == cL - 1) ? (float*)d_out : xcur;
      if (l == 0)
        k_gnode<true><<<N, 128, 0, stream>>>(
            msgbuf, row_ptr, sbuf, sold, vbuf, vold, Amat + (size_t)l * cNT * 64 * 96,
            Bmat + (size_t)l * cNT * 1024, Ws + l * 4096, Wv + l * 1024, Wproj, nattr,
            hArr, mixArr, l, xout, N);
      else
        k_gnode<false><<<N, 128, 0, stream>>>(
            msgbuf, row_ptr, sbuf, sold, vbuf, vold, Amat + (size_t)l * cNT * 64 * 96,
            Bmat + (size_t)l * cNT * 1024, Ws + l * 4096, Wv + l * 1024, Wproj, nattr,
            hArr, mixArr, l, xout, N);
    }
  } else {
    // fallback: atomic path
    float* aggs = ws + base_off;
    float* aggv = aggs + (size_t)N * 96;
    for (int l = 0; l < cL; ++l) {
      hipMemsetAsync(aggs, 0, sizeof(float) * (size_t)N * 192, stream);
      if (l == 0)
        k_edge<true><<<(E + 255) / 256, 256, 0, stream>>>(
            xcur, sbuf, vbuf, esrc, edst, fc1T + l * 1024, b1 + l * 64, fc2T + l * 12288,
            Wsv + l * 4096, Wvs + l * 6144, aggs, aggv, E);
      else
        k_edge<false><<<(E + 255) / 256, 256, 0, stream>>>(
            xcur, sbuf, vbuf, esrc, edst, fc1T + l * 1024, b1 + l * 64, fc2T + l * 12288,
            Wsv + l * 4096, Wvs + l * 6144, aggs, aggv, E);
      float* xout = (l == cL - 1) ? (float*)d_out : xcur;
      k_node<<<N, 128, 0, stream>>>(sbuf, sold, vbuf, vold, aggs, aggv,
                                    Amat + (size_t)l * cNT * 64 * 96,
                                    Bmat + (size_t)l * cNT * 1024, Ws + l * 4096,
                                    Wv + l * 1024, Wproj, nattr, hArr, mixArr, l, xout, N);
    }
  }
}